// Round 10
// baseline (969.835 us; speedup 1.0000x reference)
//
#include <hip/hip_runtime.h>
#include <hip/hip_fp16.h>
#include <math.h>

#define L 64
#define FIXS 65536.0f     // 2^16 fixed-point scale; attr-sum field = 24 bits, count = 8 bits
#define WAITCNT_LGKM0 0xC07F   // vmcnt=63, expcnt=7, lgkmcnt=0

// f32 += f16 * f32 without explicit cvt (v_fma_mix_f32: converts f16 operand to
// f32 exactly, then f32 FMA -> bit-identical to cvt+fma, one instruction).
#define FMAMIX_LO(acc, pkh, ws) \
    asm("v_fma_mix_f32 %0, %1, %2, %0 op_sel:[0,0,0] op_sel_hi:[1,0,0]" \
        : "+v"(acc) : "v"(pkh), "v"(ws))
#define FMAMIX_HI(acc, pkh, ws) \
    asm("v_fma_mix_f32 %0, %1, %2, %0 op_sel:[1,0,0] op_sel_hi:[1,0,0]" \
        : "+v"(acc) : "v"(pkh), "v"(ws))
// d = max(a+b, 0) on packed f16 pairs (2 instructions vs add+2cmp+2sel)
#define PKADDRELU(d, a, b) \
    asm("v_pk_add_f16 %0, %1, %2\n\tv_pk_max_f16 %0, %0, 0" \
        : "=v"(d) : "v"(a), "v"(b))

// k_gcn inner-loop helpers: 8-lane groups, 16B h-row slices.
// NOTE: macro params must NOT be named x/y/z/w (cpp substitutes into .x etc).
#define GLOAD(xw_, qv_, J) \
    xw_ = (unsigned)__shfl((int)mwv, (J) * 8 + grp); \
    qv_ = h4[(size_t)(xw_ & 0x1FFFFu) * 8 + sub];
#define FMA8(A, qv_, xw_) { \
    float wv_ = __half2float(__ushort_as_half((unsigned short)((xw_) >> 17))); \
    FMAMIX_LO(A[0], (qv_).x, wv_); FMAMIX_HI(A[1], (qv_).x, wv_); \
    FMAMIX_LO(A[2], (qv_).y, wv_); FMAMIX_HI(A[3], (qv_).y, wv_); \
    FMAMIX_LO(A[4], (qv_).z, wv_); FMAMIX_HI(A[5], (qv_).z, wv_); \
    FMAMIX_LO(A[6], (qv_).w, wv_); FMAMIX_HI(A[7], (qv_).w, wv_); }

// ---------- preprocessing ----------

// ONE 32-bit returning atomic per edge: packed (count<<24) | fx16(attr).
// R3 measurement: atomic cost is ~32B write-through PER OP regardless of width.
__global__ void k_hist(const int* __restrict__ col, const float* __restrict__ attr,
                       unsigned* __restrict__ degcnt,
                       int* __restrict__ rank, int E) {
    int e = blockIdx.x * blockDim.x + threadIdx.x;
    if (e < E) {
        int c = col[e];
        unsigned fx = (unsigned)(int)rintf(attr[e] * FIXS);
        unsigned old = atomicAdd(&degcnt[c], (1u << 24) | fx);
        rank[e] = (int)(old >> 24);
    }
}

__global__ void k_dinv(const unsigned* __restrict__ degcnt,
                       float* __restrict__ dinv, int* __restrict__ cntI,
                       float* __restrict__ rcnt, int N) {
    int n = blockIdx.x * blockDim.x + threadIdx.x;
    if (n < N) {
        unsigned p = degcnt[n];
        unsigned cnt = p >> 24;
        float d = (float)(p & 0xFFFFFFu) * (1.0f / FIXS);
        dinv[n] = (d > 0.f) ? (1.0f / sqrtf(fmaxf(d, 1e-30f))) : 0.f;
        cntI[n] = (int)cnt;
        unsigned c = cnt ? cnt : 1u;
        rcnt[n] = 1.0f / (float)c;
    }
}

// ---------- device-wide exclusive scan of cntI -> ptr ----------

__global__ __launch_bounds__(256) void k_scan_a(const int* __restrict__ cntI,
                                                int* __restrict__ blockSums, int N) {
    __shared__ int red[4];
    int b = blockIdx.x, t = threadIdx.x;
    int base = b * 1024 + t * 4;
    int s = 0;
    #pragma unroll
    for (int i = 0; i < 4; ++i) { int idx = base + i; if (idx < N) s += cntI[idx]; }
    #pragma unroll
    for (int off = 32; off > 0; off >>= 1) s += __shfl_down(s, off);
    if ((t & 63) == 0) red[t >> 6] = s;
    __syncthreads();
    if (t == 0) blockSums[b] = red[0] + red[1] + red[2] + red[3];
}

__global__ __launch_bounds__(1024) void k_scan_b(int* __restrict__ blockSums, int B,
                                                 int* __restrict__ ptr, int N) {
    __shared__ int sh[1024];
    int t = threadIdx.x;
    sh[t] = (t < B) ? blockSums[t] : 0;
    __syncthreads();
    for (int off = 1; off < 1024; off <<= 1) {
        int v = (t >= off) ? sh[t - off] : 0;
        __syncthreads();
        sh[t] += v;
        __syncthreads();
    }
    if (t < B) blockSums[t] = (t == 0) ? 0 : sh[t - 1];   // exclusive
    if (t == B - 1) ptr[N] = sh[t];                        // total
}

__global__ __launch_bounds__(256) void k_scan_c(const int* __restrict__ cntI,
                                                const int* __restrict__ blockSums,
                                                int* __restrict__ ptr, int N) {
    __shared__ int th[256];
    int b = blockIdx.x, t = threadIdx.x;
    int base = b * 1024 + t * 4;
    int v[4]; int s = 0;
    #pragma unroll
    for (int i = 0; i < 4; ++i) {
        int idx = base + i;
        v[i] = (idx < N) ? cntI[idx] : 0;
        s += v[i];
    }
    th[t] = s;
    __syncthreads();
    for (int off = 1; off < 256; off <<= 1) {
        int xv = (t >= off) ? th[t - off] : 0;
        __syncthreads();
        th[t] += xv;
        __syncthreads();
    }
    int pre = ((t == 0) ? 0 : th[t - 1]) + blockSums[b];
    #pragma unroll
    for (int i = 0; i < 4; ++i) {
        int idx = base + i;
        if (idx < N) ptr[idx] = pre;
        pre += v[i];
    }
}

// ---------- CSR build ----------
// record: row(17b) | fp16(norm) sans sign (15b) << 17
// Overwrites rank[e] with the absolute CSR position (gather-free k_perm).
__global__ void k_scatter(const int* __restrict__ row, const int* __restrict__ col,
                          const float* __restrict__ attr, const float* __restrict__ dinv,
                          const int* __restrict__ colptr,
                          int* __restrict__ rank,
                          unsigned* __restrict__ csrX, int E) {
    int e = blockIdx.x * blockDim.x + threadIdx.x;
    if (e < E) {
        int r = row[e], c = col[e];
        int pos = colptr[c] + rank[e];
        float nrm = dinv[r] * attr[e] * dinv[c];
        unsigned short nb = __half_as_ushort(__float2half(nrm));   // sign bit = 0
        csrX[pos] = (unsigned)r | ((unsigned)nb << 17);
        rank[e] = pos;
    }
}

// ---------- colof fill: colof[colptr[n]..colptr[n+1]) = n (contiguous runs) ----------

__global__ __launch_bounds__(256) void k_fill(const int* __restrict__ colptr,
                                              int* __restrict__ colof, int N) {
    int lane = threadIdx.x & 63;
    int wid  = (blockIdx.x * blockDim.x + threadIdx.x) >> 6;
    int nw   = (gridDim.x * blockDim.x) >> 6;
    for (int n = wid; n < N; n += nw) {
        int beg = colptr[n], end = colptr[n + 1];
        for (int p = beg + lane; p < end; p += 64) colof[p] = n;
    }
}

// ---------- encoder (fp16 h) ----------

__global__ void k_encode(const float* __restrict__ x, const float* __restrict__ w_enc,
                         const float* __restrict__ b_enc, __half* __restrict__ h, int N) {
    int idx = blockIdx.x * blockDim.x + threadIdx.x;
    if (idx < N * L) {
        int n = idx >> 6, f = idx & 63;
        h[idx] = __float2half(x[n] * w_enc[f] + b_enc[f]);
    }
}

// ---------- fused GCN layer: 4-NODE BATCHED EPILOGUE ----------
// R9 post-mortem: compiler refuses to keep Wc[64] resident (VGPR=60 despite a
// 256 budget) -> 64 rematerialized W loads per node dominated the epilogue.
// Now: aggregate 4 nodes (same csrX pipeline), stage 4 s-vectors in LDS, then
// ONE epilogue pass where each W value is loaded once and feeds 4 nodes' FMAs
// (W loads 64/node -> 16/node; fences 1 per 4 nodes; 4 indep FMA chains).

__global__ __launch_bounds__(256, 2) void k_gcn(const uint4* __restrict__ h4,
        __half* __restrict__ h_out,
        const float* __restrict__ W, const float* __restrict__ bias,
        const int* __restrict__ colptr, const unsigned* __restrict__ csrX,
        const float* __restrict__ rcnt, int N) {
    __shared__ float sm[4][4][72];     // [warp][node-in-group][64 (+pad)]
    int lane = threadIdx.x & 63;
    int warp = threadIdx.x >> 6;
    int grp  = lane >> 3;              // 8 groups of 8 lanes
    int sub  = lane & 7;               // 16B slice index within a row
    int wid  = (blockIdx.x * blockDim.x + threadIdx.x) >> 6;
    int nw   = (gridDim.x * blockDim.x) >> 6;

    float Wc[L];                       // column `lane` of W (compiler may demote)
    #pragma unroll
    for (int f = 0; f < L; ++f) Wc[f] = W[f * L + lane];
    float bl = bias[lane];

    int beg = 0, end = 0; unsigned mw = 0;
    if (wid < N) {
        beg = colptr[wid];
        end = colptr[wid + 1];
        if (beg + lane < end) mw = csrX[beg + lane];   // inactive lanes: 0 -> +0
    }

    for (int n0 = wid; n0 < N; n0 += 4 * nw) {
        int cnt = 0;
        float rc[4] = {1.f, 1.f, 1.f, 1.f};

        // ---- aggregate up to 4 nodes, staging each s-vector into LDS ----
        #pragma unroll
        for (int kk = 0; kk < 4; ++kk) {
            int n = n0 + kk * nw;
            if (n < N) {
                cnt = kk + 1;
                rc[kk] = rcnt[n];
                int nn = n + nw;
                int beg2 = 0, end2 = 0;
                if (nn < N) { beg2 = colptr[nn]; end2 = colptr[nn + 1]; }

                float va[8];
                #pragma unroll
                for (int i = 0; i < 8; ++i) va[i] = 0.f;

                auto PROC = [&](unsigned mwv, int mm) {
                    int kmax = (mm + 7) >> 3;
                    int k = 0;
                    while (k < kmax) {
                        int rem = kmax - k;    // wave-uniform branch
                        if (rem >= 4) {
                            unsigned x0, x1, x2, x3; uint4 q0, q1, q2, q3;
                            GLOAD(x0, q0, k) GLOAD(x1, q1, k + 1)
                            GLOAD(x2, q2, k + 2) GLOAD(x3, q3, k + 3)
                            FMA8(va, q0, x0) FMA8(va, q1, x1)
                            FMA8(va, q2, x2) FMA8(va, q3, x3)
                            k += 4;
                        } else if (rem == 3) {
                            unsigned x0, x1, x2; uint4 q0, q1, q2;
                            GLOAD(x0, q0, k) GLOAD(x1, q1, k + 1) GLOAD(x2, q2, k + 2)
                            FMA8(va, q0, x0) FMA8(va, q1, x1) FMA8(va, q2, x2)
                            k += 3;
                        } else if (rem == 2) {
                            unsigned x0, x1; uint4 q0, q1;
                            GLOAD(x0, q0, k) GLOAD(x1, q1, k + 1)
                            FMA8(va, q0, x0) FMA8(va, q1, x1)
                            k += 2;
                        } else {
                            unsigned x0; uint4 q0;
                            GLOAD(x0, q0, k)
                            FMA8(va, q0, x0)
                            k += 1;
                        }
                    }
                };

                int m = end - beg; if (m > 64) m = 64;
                PROC(mw, m);
                for (int base = beg + 64; base < end; base += 64) {  // rare (deg>64)
                    int mm = end - base; if (mm > 64) mm = 64;
                    unsigned mwc = 0;
                    if (lane < mm) mwc = csrX[base + lane];
                    PROC(mwc, mm);
                }

                unsigned mw2 = 0;
                if (nn < N && beg2 + lane < end2) mw2 = csrX[beg2 + lane];

                // combine the 8 edge-groups; lane sub holds feats 8*sub..8*sub+7
                float s[8];
                #pragma unroll
                for (int i = 0; i < 8; ++i) {
                    float v = va[i];
                    v += __shfl_xor(v, 8);
                    v += __shfl_xor(v, 16);
                    v += __shfl_xor(v, 32);
                    s[i] = v;
                }
                if (lane < 8) {
                    #pragma unroll
                    for (int i = 0; i < 8; ++i) sm[warp][kk][8 * lane + i] = s[i];
                }
                beg = beg2; end = end2; mw = mw2;
            }
        }

        __builtin_amdgcn_s_waitcnt(WAITCNT_LGKM0);  // stage -> epilogue RAW fence

        // ---- batched epilogue: each W value feeds up to 4 nodes ----
        float acc[4] = {0.f, 0.f, 0.f, 0.f};
        #pragma unroll
        for (int q = 0; q < 16; ++q) {
            float w0 = Wc[4 * q + 0], w1 = Wc[4 * q + 1];
            float w2 = Wc[4 * q + 2], w3 = Wc[4 * q + 3];
            #pragma unroll
            for (int kk = 0; kk < 4; ++kk) {
                float4 sv = ((const float4*)sm[warp][kk])[q];  // uniform broadcast
                acc[kk] += sv.x * w0 + sv.y * w1 + sv.z * w2 + sv.w * w3;
            }
        }
        #pragma unroll
        for (int kk = 0; kk < 4; ++kk) {
            if (kk < cnt) {
                int n = n0 + kk * nw;
                float o = acc[kk] * rc[kk] + bl;
                h_out[(size_t)n * L + lane] = __float2half(fmaxf(o, 0.f));
            }
        }
    }
}

// ---------- fused decoder node matvecs: U = h@W1[:64]+b1, V = h@W1[64:] ----------

__global__ __launch_bounds__(256, 2) void k_mv2(const __half* __restrict__ h,
        const float* __restrict__ W1, const float* __restrict__ b1,
        __half* __restrict__ U, __half* __restrict__ V, int N) {
    __shared__ float sm[4][72];
    int lane = threadIdx.x & 63;
    int warp = threadIdx.x >> 6;
    int wid  = (blockIdx.x * blockDim.x + threadIdx.x) >> 6;
    int nw   = (gridDim.x * blockDim.x) >> 6;
    float* smw = &sm[warp][0];
    float Wu[L], Wv[L];
    #pragma unroll
    for (int f = 0; f < L; ++f) Wu[f] = W1[f * L + lane];
    #pragma unroll
    for (int f = 0; f < L; ++f) Wv[f] = W1[(L + f) * L + lane];
    float bl = b1[lane];
    for (int n = wid; n < N; n += nw) {
        float hl = __half2float(h[(size_t)n * L + lane]);
        smw[lane] = hl;
        __builtin_amdgcn_s_waitcnt(WAITCNT_LGKM0);
        float a0 = 0.f, a1 = 0.f, c0 = 0.f, c1 = 0.f;
        const float4* smv = (const float4*)smw;
        #pragma unroll
        for (int q = 0; q < 16; ++q) {
            float4 sv = smv[q];
            a0 += sv.x * Wu[4 * q + 0] ; a1 += sv.y * Wu[4 * q + 1];
            a0 += sv.z * Wu[4 * q + 2] ; a1 += sv.w * Wu[4 * q + 3];
            c0 += sv.x * Wv[4 * q + 0] ; c1 += sv.y * Wv[4 * q + 1];
            c0 += sv.z * Wv[4 * q + 2] ; c1 += sv.w * Wv[4 * q + 3];
        }
        U[(size_t)n * L + lane] = __float2half((a0 + a1) + bl);
        V[(size_t)n * L + lane] = __float2half(c0 + c1);
        __builtin_amdgcn_s_waitcnt(WAITCNT_LGKM0);  // WAR guard before next store
    }
}

// ---------- decoder edge pass: EDGE-PARALLEL, 8 lanes per CSR position ----------

__global__ __launch_bounds__(256, 8) void k_edge(const __half* __restrict__ U,
        const __half* __restrict__ V, const float* __restrict__ w2,
        const float* __restrict__ b2, const unsigned* __restrict__ csrX,
        const int* __restrict__ colof, float* __restrict__ tmp, int E) {
    int sub = threadIdx.x & 7;
    float w2f[8];
    #pragma unroll
    for (int i = 0; i < 8; ++i) w2f[i] = w2[8 * sub + i];
    float b2v = b2[0];
    int tid = blockIdx.x * blockDim.x + threadIdx.x;
    int np  = (gridDim.x * blockDim.x) >> 3;
    for (int p = tid >> 3; p < E; p += np) {
        unsigned md = csrX[p];
        int r = (int)(md & 0x1FFFFu);
        int n = colof[p];
        uint4 uq = ((const uint4*)(U + (size_t)r * L))[sub];
        uint4 vq = ((const uint4*)(V + (size_t)n * L))[sub];
        float p0 = 0.f, p1 = 0.f;
        #define DOT2X(uw_, vw_, B) { unsigned t_; \
            PKADDRELU(t_, (uw_), (vw_)); \
            FMAMIX_LO(p0, t_, w2f[B]); FMAMIX_HI(p1, t_, w2f[(B) + 1]); }
        DOT2X(uq.x, vq.x, 0) DOT2X(uq.y, vq.y, 2)
        DOT2X(uq.z, vq.z, 4) DOT2X(uq.w, vq.w, 6)
        #undef DOT2X
        float pd = p0 + p1;
        pd += __shfl_xor(pd, 1);
        pd += __shfl_xor(pd, 2);
        pd += __shfl_xor(pd, 4);
        if (sub == 0) tmp[p] = pd + b2v;
    }
}

// ---------- permute CSR-ordered results back to edge order (+ softplus) ----------

__global__ void k_perm(const int* __restrict__ epos, const float* __restrict__ tmp,
                       const int* __restrict__ erow, const int* __restrict__ ecol,
                       float* __restrict__ out, int E) {
    int e = blockIdx.x * blockDim.x + threadIdx.x;
    if (e < E) {
        float val = tmp[epos[e]];
        if (erow[e] == ecol[e])
            val = fmaxf(val, 0.f) + log1pf(expf(-fabsf(val)));
        out[e] = val;
    }
}

// ---------- launch ----------

extern "C" void kernel_launch(void* const* d_in, const int* in_sizes, int n_in,
                              void* d_out, int out_size, void* d_ws, size_t ws_size,
                              hipStream_t stream) {
    const float* x     = (const float*)d_in[0];
    const float* attr  = (const float*)d_in[1];
    const float* w_enc = (const float*)d_in[2];
    const float* b_enc = (const float*)d_in[3];
    const float* c1w   = (const float*)d_in[4];
    const float* c1b   = (const float*)d_in[5];
    const float* c2w   = (const float*)d_in[6];
    const float* c2b   = (const float*)d_in[7];
    const float* dw1   = (const float*)d_in[8];
    const float* db1   = (const float*)d_in[9];
    const float* dw2   = (const float*)d_in[10];
    const float* db2   = (const float*)d_in[11];
    const int*   erow  = (const int*)d_in[12];
    const int*   ecol  = (const int*)d_in[13];
    int N = in_sizes[0];
    int E = in_sizes[1];
    float* out = (float*)d_out;

    char* w = (char*)d_ws;
    auto alloc = [&](size_t bytes) {
        char* p = w; w += (bytes + 255) & ~(size_t)255; return p;
    };
    unsigned* degcnt = (unsigned*)alloc((size_t)N * 4);  // zeroed
    size_t zbytes = (size_t)(w - (char*)d_ws);
    float* dinv   = (float*)alloc((size_t)N * 4);
    int*   cntI   = (int*)  alloc((size_t)N * 4);
    float* rcnt   = (float*)alloc((size_t)N * 4);
    int*   colptr = (int*)  alloc((size_t)(N + 1) * 4);
    int*   bsums  = (int*)  alloc(((size_t)(N + 1023) / 1024 + 1) * 4);
    int*   rank   = (int*)  alloc((size_t)E * 4);   // per-col rank, then abs CSR pos
    unsigned* csrX = (unsigned*)alloc((size_t)E * 4);
    int*   colof  = (int*)  alloc((size_t)E * 4);   // owning col per CSR position
    float* tmp    = (float*)alloc((size_t)E * 4);
    __half* hA    = (__half*)alloc((size_t)N * L * 2);   // fp16 h ping
    __half* hB    = (__half*)alloc((size_t)N * L * 2);   // fp16 h pong
    __half* hU    = (__half*)alloc((size_t)N * L * 2);   // decoder U (fp16)
    __half* hV    = (__half*)alloc((size_t)N * L * 2);   // decoder V (fp16)
    (void)ws_size; (void)n_in; (void)out_size;

    (void)hipMemsetAsync(d_ws, 0, zbytes, stream);

    int eb = (E + 255) / 256;
    int nb = (N + 255) / 256;
    int B  = (N + 1023) / 1024;     // scan chunks
    k_hist<<<eb, 256, 0, stream>>>(ecol, attr, degcnt, rank, E);
    k_dinv<<<nb, 256, 0, stream>>>(degcnt, dinv, cntI, rcnt, N);
    k_scan_a<<<B, 256, 0, stream>>>(cntI, bsums, N);
    k_scan_b<<<1, 1024, 0, stream>>>(bsums, B, colptr, N);
    k_scan_c<<<B, 256, 0, stream>>>(cntI, bsums, colptr, N);
    k_scatter<<<eb, 256, 0, stream>>>(erow, ecol, attr, dinv, colptr, rank, csrX, E);
    k_fill<<<1024, 256, 0, stream>>>(colptr, colof, N);
    k_encode<<<(N * L + 255) / 256, 256, 0, stream>>>(x, w_enc, b_enc, hA, N);

    __half* hin = hA; __half* hout = hB;
    for (int i = 0; i < 3; ++i) {
        k_gcn<<<2048, 256, 0, stream>>>((const uint4*)hin, hout, c1w + i * L * L,
                                        c1b + i * L, colptr, csrX, rcnt, N);
        __half* t = hin; hin = hout; hout = t;
        k_gcn<<<2048, 256, 0, stream>>>((const uint4*)hin, hout, c2w + i * L * L,
                                        c2b + i * L, colptr, csrX, rcnt, N);
        t = hin; hin = hout; hout = t;
    }
    // final h in hA (fp16). U -> hU (b1 folded), V -> hV
    k_mv2<<<2048, 256, 0, stream>>>(hin, dw1, db1, hU, hV, N);
    k_edge<<<2048, 256, 0, stream>>>(hU, hV, dw2, db2, csrX, colof, tmp, E);
    k_perm<<<eb, 256, 0, stream>>>(rank, tmp, erow, ecol, out, E);
}

// Round 11
// 632.085 us; speedup vs baseline: 1.5343x; 1.5343x over previous
//
#include <hip/hip_runtime.h>
#include <hip/hip_fp16.h>
#include <math.h>

#define L 64
#define FIXS 65536.0f     // 2^16 fixed-point scale; attr-sum field = 24 bits, count = 8 bits
#define WAITCNT_LGKM0 0xC07F   // vmcnt=63, expcnt=7, lgkmcnt=0

// f32 += f16 * f32 without explicit cvt (v_fma_mix_f32: converts f16 operand to
// f32 exactly, then f32 FMA -> bit-identical to cvt+fma, one instruction).
#define FMAMIX_LO(acc, pkh, ws) \
    asm("v_fma_mix_f32 %0, %1, %2, %0 op_sel:[0,0,0] op_sel_hi:[1,0,0]" \
        : "+v"(acc) : "v"(pkh), "v"(ws))
#define FMAMIX_HI(acc, pkh, ws) \
    asm("v_fma_mix_f32 %0, %1, %2, %0 op_sel:[1,0,0] op_sel_hi:[1,0,0]" \
        : "+v"(acc) : "v"(pkh), "v"(ws))
// d = max(a+b, 0) on packed f16 pairs (2 instructions vs add+2cmp+2sel)
#define PKADDRELU(d, a, b) \
    asm("v_pk_add_f16 %0, %1, %2\n\tv_pk_max_f16 %0, %0, 0" \
        : "=v"(d) : "v"(a), "v"(b))

// k_gcn inner-loop helpers: 8-lane groups, 16B h-row slices.
// NOTE: macro params must NOT be named x/y/z/w (cpp substitutes into .x etc).
#define GLOAD(xw_, qv_, J) \
    xw_ = (unsigned)__shfl((int)mwv, (J) * 8 + grp); \
    qv_ = h4[(size_t)(xw_ & 0x1FFFFu) * 8 + sub];
#define FMA8(A, qv_, xw_) { \
    float wv_ = __half2float(__ushort_as_half((unsigned short)((xw_) >> 17))); \
    FMAMIX_LO(A[0], (qv_).x, wv_); FMAMIX_HI(A[1], (qv_).x, wv_); \
    FMAMIX_LO(A[2], (qv_).y, wv_); FMAMIX_HI(A[3], (qv_).y, wv_); \
    FMAMIX_LO(A[4], (qv_).z, wv_); FMAMIX_HI(A[5], (qv_).z, wv_); \
    FMAMIX_LO(A[6], (qv_).w, wv_); FMAMIX_HI(A[7], (qv_).w, wv_); }

// ---------- preprocessing ----------

// ONE 32-bit returning atomic per edge: packed (count<<24) | fx16(attr).
// R3 measurement: atomic cost is ~32B write-through PER OP regardless of width.
__global__ void k_hist(const int* __restrict__ col, const float* __restrict__ attr,
                       unsigned* __restrict__ degcnt,
                       int* __restrict__ rank, int E) {
    int e = blockIdx.x * blockDim.x + threadIdx.x;
    if (e < E) {
        int c = col[e];
        unsigned fx = (unsigned)(int)rintf(attr[e] * FIXS);
        unsigned old = atomicAdd(&degcnt[c], (1u << 24) | fx);
        rank[e] = (int)(old >> 24);
    }
}

__global__ void k_dinv(const unsigned* __restrict__ degcnt,
                       float* __restrict__ dinv, int* __restrict__ cntI,
                       float* __restrict__ rcnt, int N) {
    int n = blockIdx.x * blockDim.x + threadIdx.x;
    if (n < N) {
        unsigned p = degcnt[n];
        unsigned cnt = p >> 24;
        float d = (float)(p & 0xFFFFFFu) * (1.0f / FIXS);
        dinv[n] = (d > 0.f) ? (1.0f / sqrtf(fmaxf(d, 1e-30f))) : 0.f;
        cntI[n] = (int)cnt;
        unsigned c = cnt ? cnt : 1u;
        rcnt[n] = 1.0f / (float)c;
    }
}

// ---------- device-wide exclusive scan of cntI -> ptr ----------

__global__ __launch_bounds__(256) void k_scan_a(const int* __restrict__ cntI,
                                                int* __restrict__ blockSums, int N) {
    __shared__ int red[4];
    int b = blockIdx.x, t = threadIdx.x;
    int base = b * 1024 + t * 4;
    int s = 0;
    #pragma unroll
    for (int i = 0; i < 4; ++i) { int idx = base + i; if (idx < N) s += cntI[idx]; }
    #pragma unroll
    for (int off = 32; off > 0; off >>= 1) s += __shfl_down(s, off);
    if ((t & 63) == 0) red[t >> 6] = s;
    __syncthreads();
    if (t == 0) blockSums[b] = red[0] + red[1] + red[2] + red[3];
}

__global__ __launch_bounds__(1024) void k_scan_b(int* __restrict__ blockSums, int B,
                                                 int* __restrict__ ptr, int N) {
    __shared__ int sh[1024];
    int t = threadIdx.x;
    sh[t] = (t < B) ? blockSums[t] : 0;
    __syncthreads();
    for (int off = 1; off < 1024; off <<= 1) {
        int v = (t >= off) ? sh[t - off] : 0;
        __syncthreads();
        sh[t] += v;
        __syncthreads();
    }
    if (t < B) blockSums[t] = (t == 0) ? 0 : sh[t - 1];   // exclusive
    if (t == B - 1) ptr[N] = sh[t];                        // total
}

__global__ __launch_bounds__(256) void k_scan_c(const int* __restrict__ cntI,
                                                const int* __restrict__ blockSums,
                                                int* __restrict__ ptr, int N) {
    __shared__ int th[256];
    int b = blockIdx.x, t = threadIdx.x;
    int base = b * 1024 + t * 4;
    int v[4]; int s = 0;
    #pragma unroll
    for (int i = 0; i < 4; ++i) {
        int idx = base + i;
        v[i] = (idx < N) ? cntI[idx] : 0;
        s += v[i];
    }
    th[t] = s;
    __syncthreads();
    for (int off = 1; off < 256; off <<= 1) {
        int xv = (t >= off) ? th[t - off] : 0;
        __syncthreads();
        th[t] += xv;
        __syncthreads();
    }
    int pre = ((t == 0) ? 0 : th[t - 1]) + blockSums[b];
    #pragma unroll
    for (int i = 0; i < 4; ++i) {
        int idx = base + i;
        if (idx < N) ptr[idx] = pre;
        pre += v[i];
    }
}

// ---------- CSR build ----------
// record: row(17b) | fp16(norm) sans sign (15b) << 17
// Overwrites rank[e] with the absolute CSR position (gather-free k_perm).
__global__ void k_scatter(const int* __restrict__ row, const int* __restrict__ col,
                          const float* __restrict__ attr, const float* __restrict__ dinv,
                          const int* __restrict__ colptr,
                          int* __restrict__ rank,
                          unsigned* __restrict__ csrX, int E) {
    int e = blockIdx.x * blockDim.x + threadIdx.x;
    if (e < E) {
        int r = row[e], c = col[e];
        int pos = colptr[c] + rank[e];
        float nrm = dinv[r] * attr[e] * dinv[c];
        unsigned short nb = __half_as_ushort(__float2half(nrm));   // sign bit = 0
        csrX[pos] = (unsigned)r | ((unsigned)nb << 17);
        rank[e] = pos;
    }
}

// ---------- colof fill: colof[colptr[n]..colptr[n+1]) = n (contiguous runs) ----------

__global__ __launch_bounds__(256) void k_fill(const int* __restrict__ colptr,
                                              int* __restrict__ colof, int N) {
    int lane = threadIdx.x & 63;
    int wid  = (blockIdx.x * blockDim.x + threadIdx.x) >> 6;
    int nw   = (gridDim.x * blockDim.x) >> 6;
    for (int n = wid; n < N; n += nw) {
        int beg = colptr[n], end = colptr[n + 1];
        for (int p = beg + lane; p < end; p += 64) colof[p] = n;
    }
}

// ---------- encoder (fp16 h) ----------

__global__ void k_encode(const float* __restrict__ x, const float* __restrict__ w_enc,
                         const float* __restrict__ b_enc, __half* __restrict__ h, int N) {
    int idx = blockIdx.x * blockDim.x + threadIdx.x;
    if (idx < N * L) {
        int n = idx >> 6, f = idx & 63;
        h[idx] = __float2half(x[n] * w_enc[f] + b_enc[f]);
    }
}

// ---------- fused GCN layer (R8 structure + REGISTER-PINNED W column) ----------
// R9: compiler rematerializes the 64 W loads every epilogue (VGPR=60 under a
// 256 budget). R10: batching the epilogue spilled (WRITE_SIZE 12.5->133MB).
// Now: pin Wc[f] with an empty asm "+v" barrier after the load -- the value
// becomes opaque, rematerialization is illegal, so the column stays in VGPRs
// and the epilogue runs with ZERO VMEM. ~130 VGPR -> 3 waves/SIMD (same
// occupancy as measured before), minus 64 load issues + latency per node.

__global__ __launch_bounds__(256, 2) void k_gcn(const uint4* __restrict__ h4,
        __half* __restrict__ h_out,
        const float* __restrict__ W, const float* __restrict__ bias,
        const int* __restrict__ colptr, const unsigned* __restrict__ csrX,
        const float* __restrict__ rcnt, int N) {
    __shared__ float sm[4][72];        // 4 waves x 64 floats (+pad)
    int lane = threadIdx.x & 63;
    int warp = threadIdx.x >> 6;
    int grp  = lane >> 3;              // 8 groups of 8 lanes
    int sub  = lane & 7;               // 16B slice index within a row
    int wid  = (blockIdx.x * blockDim.x + threadIdx.x) >> 6;
    int nw   = (gridDim.x * blockDim.x) >> 6;
    float* smw = &sm[warp][0];

    float Wc[L];                       // column `lane` of W
    #pragma unroll
    for (int f = 0; f < L; ++f) Wc[f] = W[f * L + lane];
    #pragma unroll
    for (int f = 0; f < L; ++f) asm volatile("" : "+v"(Wc[f]));  // pin in VGPRs
    float bl = bias[lane];

    int beg = 0, end = 0; unsigned mw = 0;
    if (wid < N) {
        beg = colptr[wid];
        end = colptr[wid + 1];
        if (beg + lane < end) mw = csrX[beg + lane];   // inactive lanes: 0 -> +0
    }

    for (int n = wid; n < N; n += nw) {
        int n2 = n + nw;
        int beg2 = 0, end2 = 0;
        if (n2 < N) { beg2 = colptr[n2]; end2 = colptr[n2 + 1]; }
        float rcv = rcnt[n];

        float va[8];
        #pragma unroll
        for (int i = 0; i < 8; ++i) va[i] = 0.f;

        auto PROC = [&](unsigned mwv, int mm) {
            int kmax = (mm + 7) >> 3;
            int k = 0;
            while (k < kmax) {
                int rem = kmax - k;    // wave-uniform branch
                if (rem >= 4) {
                    unsigned x0, x1, x2, x3; uint4 q0, q1, q2, q3;
                    GLOAD(x0, q0, k) GLOAD(x1, q1, k + 1)
                    GLOAD(x2, q2, k + 2) GLOAD(x3, q3, k + 3)
                    FMA8(va, q0, x0) FMA8(va, q1, x1)
                    FMA8(va, q2, x2) FMA8(va, q3, x3)
                    k += 4;
                } else if (rem == 3) {
                    unsigned x0, x1, x2; uint4 q0, q1, q2;
                    GLOAD(x0, q0, k) GLOAD(x1, q1, k + 1) GLOAD(x2, q2, k + 2)
                    FMA8(va, q0, x0) FMA8(va, q1, x1) FMA8(va, q2, x2)
                    k += 3;
                } else if (rem == 2) {
                    unsigned x0, x1; uint4 q0, q1;
                    GLOAD(x0, q0, k) GLOAD(x1, q1, k + 1)
                    FMA8(va, q0, x0) FMA8(va, q1, x1)
                    k += 2;
                } else {
                    unsigned x0; uint4 q0;
                    GLOAD(x0, q0, k)
                    FMA8(va, q0, x0)
                    k += 1;
                }
            }
        };

        int m = end - beg; if (m > 64) m = 64;
        PROC(mw, m);
        for (int base = beg + 64; base < end; base += 64) {   // rare (deg>64)
            int mm = end - base; if (mm > 64) mm = 64;
            unsigned mwc = 0;
            if (lane < mm) mwc = csrX[base + lane];
            PROC(mwc, mm);
        }

        unsigned mw2 = 0;
        if (n2 < N && beg2 + lane < end2) mw2 = csrX[beg2 + lane];

        float s[8];
        #pragma unroll
        for (int i = 0; i < 8; ++i) {
            float v = va[i];
            v += __shfl_xor(v, 8);
            v += __shfl_xor(v, 16);
            v += __shfl_xor(v, 32);
            s[i] = v;
        }
        if (lane < 8) {
            #pragma unroll
            for (int i = 0; i < 8; ++i) smw[8 * lane + i] = s[i];
        }
        __builtin_amdgcn_s_waitcnt(WAITCNT_LGKM0);  // wave-internal LDS RAW fence
        float a0 = 0.f, a1 = 0.f, a2 = 0.f, a3 = 0.f;
        const float4* smv = (const float4*)smw;
        #pragma unroll
        for (int q = 0; q < 16; ++q) {
            float4 sv = smv[q];
            a0 += sv.x * Wc[4 * q + 0];
            a1 += sv.y * Wc[4 * q + 1];
            a2 += sv.z * Wc[4 * q + 2];
            a3 += sv.w * Wc[4 * q + 3];
        }
        float o = ((a0 + a1) + (a2 + a3)) * rcv + bl;
        h_out[(size_t)n * L + lane] = __float2half(fmaxf(o, 0.f));

        beg = beg2; end = end2; mw = mw2;
    }
}

// ---------- fused decoder node matvecs: U = h@W1[:64]+b1, V = h@W1[64:] ----------

__global__ __launch_bounds__(256, 2) void k_mv2(const __half* __restrict__ h,
        const float* __restrict__ W1, const float* __restrict__ b1,
        __half* __restrict__ U, __half* __restrict__ V, int N) {
    __shared__ float sm[4][72];
    int lane = threadIdx.x & 63;
    int warp = threadIdx.x >> 6;
    int wid  = (blockIdx.x * blockDim.x + threadIdx.x) >> 6;
    int nw   = (gridDim.x * blockDim.x) >> 6;
    float* smw = &sm[warp][0];
    float Wu[L], Wv[L];
    #pragma unroll
    for (int f = 0; f < L; ++f) Wu[f] = W1[f * L + lane];
    #pragma unroll
    for (int f = 0; f < L; ++f) Wv[f] = W1[(L + f) * L + lane];
    float bl = b1[lane];
    for (int n = wid; n < N; n += nw) {
        float hl = __half2float(h[(size_t)n * L + lane]);
        smw[lane] = hl;
        __builtin_amdgcn_s_waitcnt(WAITCNT_LGKM0);
        float a0 = 0.f, a1 = 0.f, c0 = 0.f, c1 = 0.f;
        const float4* smv = (const float4*)smw;
        #pragma unroll
        for (int q = 0; q < 16; ++q) {
            float4 sv = smv[q];
            a0 += sv.x * Wu[4 * q + 0] ; a1 += sv.y * Wu[4 * q + 1];
            a0 += sv.z * Wu[4 * q + 2] ; a1 += sv.w * Wu[4 * q + 3];
            c0 += sv.x * Wv[4 * q + 0] ; c1 += sv.y * Wv[4 * q + 1];
            c0 += sv.z * Wv[4 * q + 2] ; c1 += sv.w * Wv[4 * q + 3];
        }
        U[(size_t)n * L + lane] = __float2half((a0 + a1) + bl);
        V[(size_t)n * L + lane] = __float2half(c0 + c1);
        __builtin_amdgcn_s_waitcnt(WAITCNT_LGKM0);  // WAR guard before next store
    }
}

// ---------- decoder edge pass: EDGE-PARALLEL, 8 lanes per CSR position ----------

__global__ __launch_bounds__(256, 8) void k_edge(const __half* __restrict__ U,
        const __half* __restrict__ V, const float* __restrict__ w2,
        const float* __restrict__ b2, const unsigned* __restrict__ csrX,
        const int* __restrict__ colof, float* __restrict__ tmp, int E) {
    int sub = threadIdx.x & 7;
    float w2f[8];
    #pragma unroll
    for (int i = 0; i < 8; ++i) w2f[i] = w2[8 * sub + i];
    float b2v = b2[0];
    int tid = blockIdx.x * blockDim.x + threadIdx.x;
    int np  = (gridDim.x * blockDim.x) >> 3;
    for (int p = tid >> 3; p < E; p += np) {
        unsigned md = csrX[p];
        int r = (int)(md & 0x1FFFFu);
        int n = colof[p];
        uint4 uq = ((const uint4*)(U + (size_t)r * L))[sub];
        uint4 vq = ((const uint4*)(V + (size_t)n * L))[sub];
        float p0 = 0.f, p1 = 0.f;
        #define DOT2X(uw_, vw_, B) { unsigned t_; \
            PKADDRELU(t_, (uw_), (vw_)); \
            FMAMIX_LO(p0, t_, w2f[B]); FMAMIX_HI(p1, t_, w2f[(B) + 1]); }
        DOT2X(uq.x, vq.x, 0) DOT2X(uq.y, vq.y, 2)
        DOT2X(uq.z, vq.z, 4) DOT2X(uq.w, vq.w, 6)
        #undef DOT2X
        float pd = p0 + p1;
        pd += __shfl_xor(pd, 1);
        pd += __shfl_xor(pd, 2);
        pd += __shfl_xor(pd, 4);
        if (sub == 0) tmp[p] = pd + b2v;
    }
}

// ---------- permute CSR-ordered results back to edge order (+ softplus) ----------

__global__ void k_perm(const int* __restrict__ epos, const float* __restrict__ tmp,
                       const int* __restrict__ erow, const int* __restrict__ ecol,
                       float* __restrict__ out, int E) {
    int e = blockIdx.x * blockDim.x + threadIdx.x;
    if (e < E) {
        float val = tmp[epos[e]];
        if (erow[e] == ecol[e])
            val = fmaxf(val, 0.f) + log1pf(expf(-fabsf(val)));
        out[e] = val;
    }
}

// ---------- launch ----------

extern "C" void kernel_launch(void* const* d_in, const int* in_sizes, int n_in,
                              void* d_out, int out_size, void* d_ws, size_t ws_size,
                              hipStream_t stream) {
    const float* x     = (const float*)d_in[0];
    const float* attr  = (const float*)d_in[1];
    const float* w_enc = (const float*)d_in[2];
    const float* b_enc = (const float*)d_in[3];
    const float* c1w   = (const float*)d_in[4];
    const float* c1b   = (const float*)d_in[5];
    const float* c2w   = (const float*)d_in[6];
    const float* c2b   = (const float*)d_in[7];
    const float* dw1   = (const float*)d_in[8];
    const float* db1   = (const float*)d_in[9];
    const float* dw2   = (const float*)d_in[10];
    const float* db2   = (const float*)d_in[11];
    const int*   erow  = (const int*)d_in[12];
    const int*   ecol  = (const int*)d_in[13];
    int N = in_sizes[0];
    int E = in_sizes[1];
    float* out = (float*)d_out;

    char* w = (char*)d_ws;
    auto alloc = [&](size_t bytes) {
        char* p = w; w += (bytes + 255) & ~(size_t)255; return p;
    };
    unsigned* degcnt = (unsigned*)alloc((size_t)N * 4);  // zeroed
    size_t zbytes = (size_t)(w - (char*)d_ws);
    float* dinv   = (float*)alloc((size_t)N * 4);
    int*   cntI   = (int*)  alloc((size_t)N * 4);
    float* rcnt   = (float*)alloc((size_t)N * 4);
    int*   colptr = (int*)  alloc((size_t)(N + 1) * 4);
    int*   bsums  = (int*)  alloc(((size_t)(N + 1023) / 1024 + 1) * 4);
    int*   rank   = (int*)  alloc((size_t)E * 4);   // per-col rank, then abs CSR pos
    unsigned* csrX = (unsigned*)alloc((size_t)E * 4);
    int*   colof  = (int*)  alloc((size_t)E * 4);   // owning col per CSR position
    float* tmp    = (float*)alloc((size_t)E * 4);
    __half* hA    = (__half*)alloc((size_t)N * L * 2);   // fp16 h ping
    __half* hB    = (__half*)alloc((size_t)N * L * 2);   // fp16 h pong
    __half* hU    = (__half*)alloc((size_t)N * L * 2);   // decoder U (fp16)
    __half* hV    = (__half*)alloc((size_t)N * L * 2);   // decoder V (fp16)
    (void)ws_size; (void)n_in; (void)out_size;

    (void)hipMemsetAsync(d_ws, 0, zbytes, stream);

    int eb = (E + 255) / 256;
    int nb = (N + 255) / 256;
    int B  = (N + 1023) / 1024;     // scan chunks
    k_hist<<<eb, 256, 0, stream>>>(ecol, attr, degcnt, rank, E);
    k_dinv<<<nb, 256, 0, stream>>>(degcnt, dinv, cntI, rcnt, N);
    k_scan_a<<<B, 256, 0, stream>>>(cntI, bsums, N);
    k_scan_b<<<1, 1024, 0, stream>>>(bsums, B, colptr, N);
    k_scan_c<<<B, 256, 0, stream>>>(cntI, bsums, colptr, N);
    k_scatter<<<eb, 256, 0, stream>>>(erow, ecol, attr, dinv, colptr, rank, csrX, E);
    k_fill<<<1024, 256, 0, stream>>>(colptr, colof, N);
    k_encode<<<(N * L + 255) / 256, 256, 0, stream>>>(x, w_enc, b_enc, hA, N);

    __half* hin = hA; __half* hout = hB;
    for (int i = 0; i < 3; ++i) {
        k_gcn<<<2048, 256, 0, stream>>>((const uint4*)hin, hout, c1w + i * L * L,
                                        c1b + i * L, colptr, csrX, rcnt, N);
        __half* t = hin; hin = hout; hout = t;
        k_gcn<<<2048, 256, 0, stream>>>((const uint4*)hin, hout, c2w + i * L * L,
                                        c2b + i * L, colptr, csrX, rcnt, N);
        t = hin; hin = hout; hout = t;
    }
    // final h in hA (fp16). U -> hU (b1 folded), V -> hV
    k_mv2<<<2048, 256, 0, stream>>>(hin, dw1, db1, hU, hV, N);
    k_edge<<<2048, 256, 0, stream>>>(hU, hV, dw2, db2, csrX, colof, tmp, E);
    k_perm<<<eb, 256, 0, stream>>>(rank, tmp, erow, ecol, out, E);
}

// Round 12
// 583.225 us; speedup vs baseline: 1.6629x; 1.0838x over previous
//
#include <hip/hip_runtime.h>
#include <hip/hip_fp16.h>
#include <math.h>

#define L 64
#define FIXS 65536.0f     // 2^16 fixed-point scale; attr-sum field = 24 bits, count = 8 bits
#define WAITCNT_LGKM0 0xC07F   // vmcnt=63, expcnt=7, lgkmcnt=0

typedef _Float16 f16x8 __attribute__((ext_vector_type(8)));
typedef float f32x4 __attribute__((ext_vector_type(4)));

// f32 += f16 * f32 without explicit cvt (v_fma_mix_f32: converts f16 operand to
// f32 exactly, then f32 FMA -> bit-identical to cvt+fma, one instruction).
#define FMAMIX_LO(acc, pkh, ws) \
    asm("v_fma_mix_f32 %0, %1, %2, %0 op_sel:[0,0,0] op_sel_hi:[1,0,0]" \
        : "+v"(acc) : "v"(pkh), "v"(ws))
#define FMAMIX_HI(acc, pkh, ws) \
    asm("v_fma_mix_f32 %0, %1, %2, %0 op_sel:[1,0,0] op_sel_hi:[1,0,0]" \
        : "+v"(acc) : "v"(pkh), "v"(ws))
// d = max(a+b, 0) on packed f16 pairs (2 instructions vs add+2cmp+2sel)
#define PKADDRELU(d, a, b) \
    asm("v_pk_add_f16 %0, %1, %2\n\tv_pk_max_f16 %0, %0, 0" \
        : "=v"(d) : "v"(a), "v"(b))

// gather-loop helpers: 8-lane groups, 16B row slices.
// NOTE: macro params must NOT be named x/y/z/w (cpp substitutes into .x etc).
#define GLOAD(xw_, qv_, J) \
    xw_ = (unsigned)__shfl((int)mwv, (J) * 8 + grp); \
    qv_ = h4[(size_t)(xw_ & 0x1FFFFu) * 8 + sub];
#define FMA8(A, qv_, xw_) { \
    float wv_ = __half2float(__ushort_as_half((unsigned short)((xw_) >> 17))); \
    FMAMIX_LO(A[0], (qv_).x, wv_); FMAMIX_HI(A[1], (qv_).x, wv_); \
    FMAMIX_LO(A[2], (qv_).y, wv_); FMAMIX_HI(A[3], (qv_).y, wv_); \
    FMAMIX_LO(A[4], (qv_).z, wv_); FMAMIX_HI(A[5], (qv_).z, wv_); \
    FMAMIX_LO(A[6], (qv_).w, wv_); FMAMIX_HI(A[7], (qv_).w, wv_); }

// ---------- preprocessing ----------

__global__ void k_hist(const int* __restrict__ col, const float* __restrict__ attr,
                       unsigned* __restrict__ degcnt,
                       int* __restrict__ rank, int E) {
    int e = blockIdx.x * blockDim.x + threadIdx.x;
    if (e < E) {
        int c = col[e];
        unsigned fx = (unsigned)(int)rintf(attr[e] * FIXS);
        unsigned old = atomicAdd(&degcnt[c], (1u << 24) | fx);
        rank[e] = (int)(old >> 24);
    }
}

__global__ void k_dinv(const unsigned* __restrict__ degcnt,
                       float* __restrict__ dinv, int* __restrict__ cntI,
                       float* __restrict__ rcnt, int N) {
    int n = blockIdx.x * blockDim.x + threadIdx.x;
    if (n < N) {
        unsigned p = degcnt[n];
        unsigned cnt = p >> 24;
        float d = (float)(p & 0xFFFFFFu) * (1.0f / FIXS);
        dinv[n] = (d > 0.f) ? (1.0f / sqrtf(fmaxf(d, 1e-30f))) : 0.f;
        cntI[n] = (int)cnt;
        unsigned c = cnt ? cnt : 1u;
        rcnt[n] = 1.0f / (float)c;
    }
}

// ---------- device-wide exclusive scan of cntI -> ptr ----------

__global__ __launch_bounds__(256) void k_scan_a(const int* __restrict__ cntI,
                                                int* __restrict__ blockSums, int N) {
    __shared__ int red[4];
    int b = blockIdx.x, t = threadIdx.x;
    int base = b * 1024 + t * 4;
    int s = 0;
    #pragma unroll
    for (int i = 0; i < 4; ++i) { int idx = base + i; if (idx < N) s += cntI[idx]; }
    #pragma unroll
    for (int off = 32; off > 0; off >>= 1) s += __shfl_down(s, off);
    if ((t & 63) == 0) red[t >> 6] = s;
    __syncthreads();
    if (t == 0) blockSums[b] = red[0] + red[1] + red[2] + red[3];
}

__global__ __launch_bounds__(1024) void k_scan_b(int* __restrict__ blockSums, int B,
                                                 int* __restrict__ ptr, int N) {
    __shared__ int sh[1024];
    int t = threadIdx.x;
    sh[t] = (t < B) ? blockSums[t] : 0;
    __syncthreads();
    for (int off = 1; off < 1024; off <<= 1) {
        int v = (t >= off) ? sh[t - off] : 0;
        __syncthreads();
        sh[t] += v;
        __syncthreads();
    }
    if (t < B) blockSums[t] = (t == 0) ? 0 : sh[t - 1];   // exclusive
    if (t == B - 1) ptr[N] = sh[t];                        // total
}

__global__ __launch_bounds__(256) void k_scan_c(const int* __restrict__ cntI,
                                                const int* __restrict__ blockSums,
                                                int* __restrict__ ptr, int N) {
    __shared__ int th[256];
    int b = blockIdx.x, t = threadIdx.x;
    int base = b * 1024 + t * 4;
    int v[4]; int s = 0;
    #pragma unroll
    for (int i = 0; i < 4; ++i) {
        int idx = base + i;
        v[i] = (idx < N) ? cntI[idx] : 0;
        s += v[i];
    }
    th[t] = s;
    __syncthreads();
    for (int off = 1; off < 256; off <<= 1) {
        int xv = (t >= off) ? th[t - off] : 0;
        __syncthreads();
        th[t] += xv;
        __syncthreads();
    }
    int pre = ((t == 0) ? 0 : th[t - 1]) + blockSums[b];
    #pragma unroll
    for (int i = 0; i < 4; ++i) {
        int idx = base + i;
        if (idx < N) ptr[idx] = pre;
        pre += v[i];
    }
}

// ---------- CSR build ----------

__global__ void k_scatter(const int* __restrict__ row, const int* __restrict__ col,
                          const float* __restrict__ attr, const float* __restrict__ dinv,
                          const int* __restrict__ colptr,
                          int* __restrict__ rank,
                          unsigned* __restrict__ csrX, int E) {
    int e = blockIdx.x * blockDim.x + threadIdx.x;
    if (e < E) {
        int r = row[e], c = col[e];
        int pos = colptr[c] + rank[e];
        float nrm = dinv[r] * attr[e] * dinv[c];
        unsigned short nb = __half_as_ushort(__float2half(nrm));   // sign bit = 0
        csrX[pos] = (unsigned)r | ((unsigned)nb << 17);
        rank[e] = pos;
    }
}

// ---------- colof fill: colof[colptr[n]..colptr[n+1]) = n (contiguous runs) ----------

__global__ __launch_bounds__(256) void k_fill(const int* __restrict__ colptr,
                                              int* __restrict__ colof, int N) {
    int lane = threadIdx.x & 63;
    int wid  = (blockIdx.x * blockDim.x + threadIdx.x) >> 6;
    int nw   = (gridDim.x * blockDim.x) >> 6;
    for (int n = wid; n < N; n += nw) {
        int beg = colptr[n], end = colptr[n + 1];
        for (int p = beg + lane; p < end; p += 64) colof[p] = n;
    }
}

// ---------- encoder folding: g1 = x * (w_enc@W1) + b_enc@W1 (rank-1) ----------

__global__ void k_fold(const float* __restrict__ w_enc, const float* __restrict__ b_enc,
                       const float* __restrict__ W1,
                       float* __restrict__ we1, float* __restrict__ be1) {
    int j = threadIdx.x;
    if (j < L) {
        float a = 0.f, b = 0.f;
        for (int f = 0; f < L; ++f) {
            float wv = W1[f * L + j];
            a += w_enc[f] * wv;
            b += b_enc[f] * wv;
        }
        we1[j] = a; be1[j] = b;
    }
}

__global__ void k_encode(const float* __restrict__ x, const float* __restrict__ we1,
                         const float* __restrict__ be1, __half* __restrict__ g, int N) {
    int idx = blockIdx.x * blockDim.x + threadIdx.x;
    if (idx < N * L) {
        int n = idx >> 6, f = idx & 63;
        g[idx] = __float2half(x[n] * we1[f] + be1[f]);
    }
}

// ---------- gather-aggregate: h_out = relu(rcnt * sum(norm*g[row]) + b) ----------
// R7-proven structure (~45us): no W, no LDS, ~56 VGPR -> high occupancy.

__global__ __launch_bounds__(256, 6) void k_agg(const uint4* __restrict__ h4,
        __half* __restrict__ h_out, const float* __restrict__ bias,
        const int* __restrict__ colptr, const unsigned* __restrict__ csrX,
        const float* __restrict__ rcnt, int N) {
    int lane = threadIdx.x & 63;
    int grp  = lane >> 3;              // 8 groups of 8 lanes
    int sub  = lane & 7;               // 16B slice index within a row
    int wid  = (blockIdx.x * blockDim.x + threadIdx.x) >> 6;
    int nw   = (gridDim.x * blockDim.x) >> 6;

    float bl8[8];                      // bias for features 8*sub..8*sub+7
    #pragma unroll
    for (int i = 0; i < 8; ++i) bl8[i] = bias[8 * sub + i];

    int beg = 0, end = 0; unsigned mw = 0;
    if (wid < N) {
        beg = colptr[wid];
        end = colptr[wid + 1];
        if (beg + lane < end) mw = csrX[beg + lane];   // inactive lanes: 0 -> +0
    }

    for (int n = wid; n < N; n += nw) {
        int n2 = n + nw;
        int beg2 = 0, end2 = 0;
        if (n2 < N) { beg2 = colptr[n2]; end2 = colptr[n2 + 1]; }
        float rcv = rcnt[n];

        float va[8];
        #pragma unroll
        for (int i = 0; i < 8; ++i) va[i] = 0.f;

        auto PROC = [&](unsigned mwv, int mm) {
            int kmax = (mm + 7) >> 3;
            int k = 0;
            while (k < kmax) {
                int rem = kmax - k;    // wave-uniform branch
                if (rem >= 4) {
                    unsigned x0, x1, x2, x3; uint4 q0, q1, q2, q3;
                    GLOAD(x0, q0, k) GLOAD(x1, q1, k + 1)
                    GLOAD(x2, q2, k + 2) GLOAD(x3, q3, k + 3)
                    FMA8(va, q0, x0) FMA8(va, q1, x1)
                    FMA8(va, q2, x2) FMA8(va, q3, x3)
                    k += 4;
                } else if (rem == 3) {
                    unsigned x0, x1, x2; uint4 q0, q1, q2;
                    GLOAD(x0, q0, k) GLOAD(x1, q1, k + 1) GLOAD(x2, q2, k + 2)
                    FMA8(va, q0, x0) FMA8(va, q1, x1) FMA8(va, q2, x2)
                    k += 3;
                } else if (rem == 2) {
                    unsigned x0, x1; uint4 q0, q1;
                    GLOAD(x0, q0, k) GLOAD(x1, q1, k + 1)
                    FMA8(va, q0, x0) FMA8(va, q1, x1)
                    k += 2;
                } else {
                    unsigned x0; uint4 q0;
                    GLOAD(x0, q0, k)
                    FMA8(va, q0, x0)
                    k += 1;
                }
            }
        };

        int m = end - beg; if (m > 64) m = 64;
        PROC(mw, m);
        for (int base = beg + 64; base < end; base += 64) {   // rare (deg>64)
            int mm = end - base; if (mm > 64) mm = 64;
            unsigned mwc = 0;
            if (lane < mm) mwc = csrX[base + lane];
            PROC(mwc, mm);
        }

        unsigned mw2 = 0;
        if (n2 < N && beg2 + lane < end2) mw2 = csrX[beg2 + lane];

        float s[8];
        #pragma unroll
        for (int i = 0; i < 8; ++i) {
            float v = va[i];
            v += __shfl_xor(v, 8);
            v += __shfl_xor(v, 16);
            v += __shfl_xor(v, 32);
            s[i] = v;
        }
        if (lane < 8) {                // sub == lane: features 8*lane..8*lane+7
            unsigned u[4];
            #pragma unroll
            for (int i = 0; i < 4; ++i) {
                float oa = fmaxf(s[2 * i]     * rcv + bl8[2 * i],     0.f);
                float ob = fmaxf(s[2 * i + 1] * rcv + bl8[2 * i + 1], 0.f);
                u[i] = (unsigned)__half_as_ushort(__float2half(oa))
                     | ((unsigned)__half_as_ushort(__float2half(ob)) << 16);
            }
            uint4 st; st.x = u[0]; st.y = u[1]; st.z = u[2]; st.w = u[3];
            ((uint4*)h_out)[(size_t)n * 8 + lane] = st;
        }

        beg = beg2; end = end2; mw = mw2;
    }
}

// ---------- dense transform g = h @ W via MFMA (split-fp16 W: full f32 accuracy) ----------
// [N x 64] @ [64 x 64]: wave tile = 16 nodes. A: lane holds 8 K-contiguous fp16
// at row=lane&15, k-offset=(lane>>4)*8 (m92/m97-verified layout). W = Wh + Wl
// (fp16 hi + fp16 residual) -> h@Wh + h@Wl == h@W to ~2^-22 rel (better than
// the old f32-FMA matvec). D: col=lane&15, row=(lane>>4)*4+reg (m89-verified).

__global__ __launch_bounds__(256) void k_gx(const __half* __restrict__ h,
        const float* __restrict__ W, __half* __restrict__ g, int N) {
    int lane = threadIdx.x & 63;
    int wid  = (blockIdx.x * blockDim.x + threadIdx.x) >> 6;
    int nw   = (gridDim.x * blockDim.x) >> 6;
    int r16  = lane & 15;
    int q4   = lane >> 4;

    f16x8 bh[4][2], bl[4][2];          // B frags: [col-tile][k-step]
    #pragma unroll
    for (int t = 0; t < 4; ++t)
        #pragma unroll
        for (int ks = 0; ks < 2; ++ks)
            #pragma unroll
            for (int i = 0; i < 8; ++i) {
                int k = ks * 32 + q4 * 8 + i;
                float wv = W[k * L + t * 16 + r16];
                _Float16 hi = (_Float16)wv;
                bh[t][ks][i] = hi;
                bl[t][ks][i] = (_Float16)(wv - (float)hi);
            }

    int tiles = (N + 15) >> 4;
    for (int tt = wid; tt < tiles; tt += nw) {
        int n0 = tt << 4;
        int row = n0 + r16; if (row >= N) row = N - 1;
        f16x8 a0 = *(const f16x8*)(h + (size_t)row * L + q4 * 8);
        f16x8 a1 = *(const f16x8*)(h + (size_t)row * L + 32 + q4 * 8);
        #pragma unroll
        for (int t = 0; t < 4; ++t) {
            f32x4 acc = {0.f, 0.f, 0.f, 0.f};
            acc = __builtin_amdgcn_mfma_f32_16x16x32_f16(a0, bl[t][0], acc, 0, 0, 0);
            acc = __builtin_amdgcn_mfma_f32_16x16x32_f16(a1, bl[t][1], acc, 0, 0, 0);
            acc = __builtin_amdgcn_mfma_f32_16x16x32_f16(a0, bh[t][0], acc, 0, 0, 0);
            acc = __builtin_amdgcn_mfma_f32_16x16x32_f16(a1, bh[t][1], acc, 0, 0, 0);
            #pragma unroll
            for (int r = 0; r < 4; ++r) {
                int node = n0 + q4 * 4 + r;
                if (node < N)
                    g[(size_t)node * L + t * 16 + r16] = __float2half(acc[r]);
            }
        }
    }
}

// ---------- fused decoder node matvecs: U = h@W1[:64]+b1, V = h@W1[64:] ----------

__global__ __launch_bounds__(256, 2) void k_mv2(const __half* __restrict__ h,
        const float* __restrict__ W1, const float* __restrict__ b1,
        __half* __restrict__ U, __half* __restrict__ V, int N) {
    __shared__ float sm[4][72];
    int lane = threadIdx.x & 63;
    int warp = threadIdx.x >> 6;
    int wid  = (blockIdx.x * blockDim.x + threadIdx.x) >> 6;
    int nw   = (gridDim.x * blockDim.x) >> 6;
    float* smw = &sm[warp][0];
    float Wu[L], Wv[L];
    #pragma unroll
    for (int f = 0; f < L; ++f) Wu[f] = W1[f * L + lane];
    #pragma unroll
    for (int f = 0; f < L; ++f) Wv[f] = W1[(L + f) * L + lane];
    float bl = b1[lane];
    for (int n = wid; n < N; n += nw) {
        float hl = __half2float(h[(size_t)n * L + lane]);
        smw[lane] = hl;
        __builtin_amdgcn_s_waitcnt(WAITCNT_LGKM0);
        float a0 = 0.f, a1 = 0.f, c0 = 0.f, c1 = 0.f;
        const float4* smv = (const float4*)smw;
        #pragma unroll
        for (int q = 0; q < 16; ++q) {
            float4 sv = smv[q];
            a0 += sv.x * Wu[4 * q + 0] ; a1 += sv.y * Wu[4 * q + 1];
            a0 += sv.z * Wu[4 * q + 2] ; a1 += sv.w * Wu[4 * q + 3];
            c0 += sv.x * Wv[4 * q + 0] ; c1 += sv.y * Wv[4 * q + 1];
            c0 += sv.z * Wv[4 * q + 2] ; c1 += sv.w * Wv[4 * q + 3];
        }
        U[(size_t)n * L + lane] = __float2half((a0 + a1) + bl);
        V[(size_t)n * L + lane] = __float2half(c0 + c1);
        __builtin_amdgcn_s_waitcnt(WAITCNT_LGKM0);  // WAR guard before next store
    }
}

// ---------- decoder edge pass: EDGE-PARALLEL, 8 lanes per CSR position ----------

__global__ __launch_bounds__(256, 8) void k_edge(const __half* __restrict__ U,
        const __half* __restrict__ V, const float* __restrict__ w2,
        const float* __restrict__ b2, const unsigned* __restrict__ csrX,
        const int* __restrict__ colof, float* __restrict__ tmp, int E) {
    int sub = threadIdx.x & 7;
    float w2f[8];
    #pragma unroll
    for (int i = 0; i < 8; ++i) w2f[i] = w2[8 * sub + i];
    float b2v = b2[0];
    int tid = blockIdx.x * blockDim.x + threadIdx.x;
    int np  = (gridDim.x * blockDim.x) >> 3;
    for (int p = tid >> 3; p < E; p += np) {
        unsigned md = csrX[p];
        int r = (int)(md & 0x1FFFFu);
        int n = colof[p];
        uint4 uq = ((const uint4*)(U + (size_t)r * L))[sub];
        uint4 vq = ((const uint4*)(V + (size_t)n * L))[sub];
        float p0 = 0.f, p1 = 0.f;
        #define DOT2X(uw_, vw_, B) { unsigned t_; \
            PKADDRELU(t_, (uw_), (vw_)); \
            FMAMIX_LO(p0, t_, w2f[B]); FMAMIX_HI(p1, t_, w2f[(B) + 1]); }
        DOT2X(uq.x, vq.x, 0) DOT2X(uq.y, vq.y, 2)
        DOT2X(uq.z, vq.z, 4) DOT2X(uq.w, vq.w, 6)
        #undef DOT2X
        float pd = p0 + p1;
        pd += __shfl_xor(pd, 1);
        pd += __shfl_xor(pd, 2);
        pd += __shfl_xor(pd, 4);
        if (sub == 0) tmp[p] = pd + b2v;
    }
}

// ---------- permute CSR-ordered results back to edge order (+ softplus) ----------

__global__ void k_perm(const int* __restrict__ epos, const float* __restrict__ tmp,
                       const int* __restrict__ erow, const int* __restrict__ ecol,
                       float* __restrict__ out, int E) {
    int e = blockIdx.x * blockDim.x + threadIdx.x;
    if (e < E) {
        float val = tmp[epos[e]];
        if (erow[e] == ecol[e])
            val = fmaxf(val, 0.f) + log1pf(expf(-fabsf(val)));
        out[e] = val;
    }
}

// ---------- launch ----------

extern "C" void kernel_launch(void* const* d_in, const int* in_sizes, int n_in,
                              void* d_out, int out_size, void* d_ws, size_t ws_size,
                              hipStream_t stream) {
    const float* x     = (const float*)d_in[0];
    const float* attr  = (const float*)d_in[1];
    const float* w_enc = (const float*)d_in[2];
    const float* b_enc = (const float*)d_in[3];
    const float* c1w   = (const float*)d_in[4];
    const float* c1b   = (const float*)d_in[5];
    const float* c2w   = (const float*)d_in[6];
    const float* c2b   = (const float*)d_in[7];
    const float* dw1   = (const float*)d_in[8];
    const float* db1   = (const float*)d_in[9];
    const float* dw2   = (const float*)d_in[10];
    const float* db2   = (const float*)d_in[11];
    const int*   erow  = (const int*)d_in[12];
    const int*   ecol  = (const int*)d_in[13];
    int N = in_sizes[0];
    int E = in_sizes[1];
    float* out = (float*)d_out;

    char* w = (char*)d_ws;
    auto alloc = [&](size_t bytes) {
        char* p = w; w += (bytes + 255) & ~(size_t)255; return p;
    };
    unsigned* degcnt = (unsigned*)alloc((size_t)N * 4);  // zeroed
    size_t zbytes = (size_t)(w - (char*)d_ws);
    float* dinv   = (float*)alloc((size_t)N * 4);
    int*   cntI   = (int*)  alloc((size_t)N * 4);
    float* rcnt   = (float*)alloc((size_t)N * 4);
    int*   colptr = (int*)  alloc((size_t)(N + 1) * 4);
    int*   bsums  = (int*)  alloc(((size_t)(N + 1023) / 1024 + 1) * 4);
    float* we1    = (float*)alloc(L * 4);
    float* be1    = (float*)alloc(L * 4);
    int*   rank   = (int*)  alloc((size_t)E * 4);   // per-col rank, then abs CSR pos
    unsigned* csrX = (unsigned*)alloc((size_t)E * 4);
    int*   colof  = (int*)  alloc((size_t)E * 4);   // owning col per CSR position
    float* tmp    = (float*)alloc((size_t)E * 4);
    __half* hA    = (__half*)alloc((size_t)N * L * 2);   // fp16 h ping
    __half* hB    = (__half*)alloc((size_t)N * L * 2);   // fp16 h pong
    __half* hU    = (__half*)alloc((size_t)N * L * 2);   // decoder U; aliases g
    __half* hV    = (__half*)alloc((size_t)N * L * 2);   // decoder V (fp16)
    __half* gbuf  = hU;   // g buffer lives in hU until k_mv2 (which reads hB)
    (void)ws_size; (void)n_in; (void)out_size;

    (void)hipMemsetAsync(d_ws, 0, zbytes, stream);

    int eb = (E + 255) / 256;
    int nb = (N + 255) / 256;
    int B  = (N + 1023) / 1024;     // scan chunks
    k_hist<<<eb, 256, 0, stream>>>(ecol, attr, degcnt, rank, E);
    k_dinv<<<nb, 256, 0, stream>>>(degcnt, dinv, cntI, rcnt, N);
    k_scan_a<<<B, 256, 0, stream>>>(cntI, bsums, N);
    k_scan_b<<<1, 1024, 0, stream>>>(bsums, B, colptr, N);
    k_scan_c<<<B, 256, 0, stream>>>(cntI, bsums, colptr, N);
    k_scatter<<<eb, 256, 0, stream>>>(erow, ecol, attr, dinv, colptr, rank, csrX, E);
    k_fill<<<1024, 256, 0, stream>>>(colptr, colof, N);

    // encoder folded with conv1_0's W: g1 = x * (w_enc@W) + b_enc@W
    k_fold<<<1, 64, 0, stream>>>(w_enc, b_enc, c1w, we1, be1);
    k_encode<<<(N * L + 255) / 256, 256, 0, stream>>>(x, we1, be1, gbuf, N);

    // 6 conv layers: agg(g) -> h; then g = h @ W_next (except after the last)
    const float* Ws[6] = {c1w,             c2w,
                          c1w + L * L,     c2w + L * L,
                          c1w + 2 * L * L, c2w + 2 * L * L};
    const float* Bs[6] = {c1b,         c2b,
                          c1b + L,     c2b + L,
                          c1b + 2 * L, c2b + 2 * L};
    (void)Ws[0];   // folded into the encoder
    __half* outs[2] = {hA, hB};
    __half* hcur = nullptr;
    for (int j = 0; j < 6; ++j) {
        hcur = outs[j & 1];
        k_agg<<<2048, 256, 0, stream>>>((const uint4*)gbuf, hcur, Bs[j],
                                        colptr, csrX, rcnt, N);
        if (j < 5)
            k_gx<<<512, 256, 0, stream>>>(hcur, Ws[j + 1], gbuf, N);
    }
    // h_final in hcur (= hB). U -> hU (b1 folded), V -> hV
    k_mv2<<<2048, 256, 0, stream>>>(hcur, dw1, db1, hU, hV, N);
    k_edge<<<2048, 256, 0, stream>>>(hU, hV, dw2, db2, csrX, colof, tmp, E);
    k_perm<<<eb, 256, 0, stream>>>(rank, tmp, erow, ecol, out, E);
}

// Round 13
// 563.225 us; speedup vs baseline: 1.7219x; 1.0355x over previous
//
#include <hip/hip_runtime.h>
#include <hip/hip_fp16.h>
#include <math.h>

#define L 64
#define FIXS 65536.0f     // 2^16 fixed-point scale; attr-sum field = 24 bits, count = 8 bits
#define WAITCNT_LGKM0 0xC07F   // vmcnt=63, expcnt=7, lgkmcnt=0

typedef _Float16 f16x8 __attribute__((ext_vector_type(8)));
typedef float f32x4 __attribute__((ext_vector_type(4)));

// f32 += f16 * f32 without explicit cvt (v_fma_mix_f32: converts f16 operand to
// f32 exactly, then f32 FMA -> bit-identical to cvt+fma, one instruction).
#define FMAMIX_LO(acc, pkh, ws) \
    asm("v_fma_mix_f32 %0, %1, %2, %0 op_sel:[0,0,0] op_sel_hi:[1,0,0]" \
        : "+v"(acc) : "v"(pkh), "v"(ws))
#define FMAMIX_HI(acc, pkh, ws) \
    asm("v_fma_mix_f32 %0, %1, %2, %0 op_sel:[1,0,0] op_sel_hi:[1,0,0]" \
        : "+v"(acc) : "v"(pkh), "v"(ws))
// d = max(a+b, 0) on packed f16 pairs (2 instructions vs add+2cmp+2sel)
#define PKADDRELU(d, a, b) \
    asm("v_pk_add_f16 %0, %1, %2\n\tv_pk_max_f16 %0, %0, 0" \
        : "=v"(d) : "v"(a), "v"(b))

// gather-loop helpers: 8-lane groups, 16B row slices.
// NOTE: macro params must NOT be named x/y/z/w (cpp substitutes into .x etc).
#define GLOAD(xw_, qv_, J) \
    xw_ = (unsigned)__shfl((int)mwv, (J) * 8 + grp); \
    qv_ = h4[(size_t)(xw_ & 0x1FFFFu) * 8 + sub];
#define FMA8(A, qv_, xw_) { \
    float wv_ = __half2float(__ushort_as_half((unsigned short)((xw_) >> 17))); \
    FMAMIX_LO(A[0], (qv_).x, wv_); FMAMIX_HI(A[1], (qv_).x, wv_); \
    FMAMIX_LO(A[2], (qv_).y, wv_); FMAMIX_HI(A[3], (qv_).y, wv_); \
    FMAMIX_LO(A[4], (qv_).z, wv_); FMAMIX_HI(A[5], (qv_).z, wv_); \
    FMAMIX_LO(A[6], (qv_).w, wv_); FMAMIX_HI(A[7], (qv_).w, wv_); }

// ---------- preprocessing ----------

__global__ void k_hist(const int* __restrict__ col, const float* __restrict__ attr,
                       unsigned* __restrict__ degcnt,
                       int* __restrict__ rank, int E) {
    int e = blockIdx.x * blockDim.x + threadIdx.x;
    if (e < E) {
        int c = col[e];
        unsigned fx = (unsigned)(int)rintf(attr[e] * FIXS);
        unsigned old = atomicAdd(&degcnt[c], (1u << 24) | fx);
        rank[e] = (int)(old >> 24);
    }
}

__global__ void k_dinv(const unsigned* __restrict__ degcnt,
                       float* __restrict__ dinv, int* __restrict__ cntI,
                       float* __restrict__ rcnt, int N) {
    int n = blockIdx.x * blockDim.x + threadIdx.x;
    if (n < N) {
        unsigned p = degcnt[n];
        unsigned cnt = p >> 24;
        float d = (float)(p & 0xFFFFFFu) * (1.0f / FIXS);
        dinv[n] = (d > 0.f) ? (1.0f / sqrtf(fmaxf(d, 1e-30f))) : 0.f;
        cntI[n] = (int)cnt;
        unsigned c = cnt ? cnt : 1u;
        rcnt[n] = 1.0f / (float)c;
    }
}

// ---------- device-wide exclusive scan of cntI -> ptr ----------

__global__ __launch_bounds__(256) void k_scan_a(const int* __restrict__ cntI,
                                                int* __restrict__ blockSums, int N) {
    __shared__ int red[4];
    int b = blockIdx.x, t = threadIdx.x;
    int base = b * 1024 + t * 4;
    int s = 0;
    #pragma unroll
    for (int i = 0; i < 4; ++i) { int idx = base + i; if (idx < N) s += cntI[idx]; }
    #pragma unroll
    for (int off = 32; off > 0; off >>= 1) s += __shfl_down(s, off);
    if ((t & 63) == 0) red[t >> 6] = s;
    __syncthreads();
    if (t == 0) blockSums[b] = red[0] + red[1] + red[2] + red[3];
}

__global__ __launch_bounds__(1024) void k_scan_b(int* __restrict__ blockSums, int B,
                                                 int* __restrict__ ptr, int N) {
    __shared__ int sh[1024];
    int t = threadIdx.x;
    sh[t] = (t < B) ? blockSums[t] : 0;
    __syncthreads();
    for (int off = 1; off < 1024; off <<= 1) {
        int v = (t >= off) ? sh[t - off] : 0;
        __syncthreads();
        sh[t] += v;
        __syncthreads();
    }
    if (t < B) blockSums[t] = (t == 0) ? 0 : sh[t - 1];   // exclusive
    if (t == B - 1) ptr[N] = sh[t];                        // total
}

__global__ __launch_bounds__(256) void k_scan_c(const int* __restrict__ cntI,
                                                const int* __restrict__ blockSums,
                                                int* __restrict__ ptr, int N) {
    __shared__ int th[256];
    int b = blockIdx.x, t = threadIdx.x;
    int base = b * 1024 + t * 4;
    int v[4]; int s = 0;
    #pragma unroll
    for (int i = 0; i < 4; ++i) {
        int idx = base + i;
        v[i] = (idx < N) ? cntI[idx] : 0;
        s += v[i];
    }
    th[t] = s;
    __syncthreads();
    for (int off = 1; off < 256; off <<= 1) {
        int xv = (t >= off) ? th[t - off] : 0;
        __syncthreads();
        th[t] += xv;
        __syncthreads();
    }
    int pre = ((t == 0) ? 0 : th[t - 1]) + blockSums[b];
    #pragma unroll
    for (int i = 0; i < 4; ++i) {
        int idx = base + i;
        if (idx < N) ptr[idx] = pre;
        pre += v[i];
    }
}

// ---------- CSR build ----------

__global__ void k_scatter(const int* __restrict__ row, const int* __restrict__ col,
                          const float* __restrict__ attr, const float* __restrict__ dinv,
                          const int* __restrict__ colptr,
                          int* __restrict__ rank,
                          unsigned* __restrict__ csrX, int E) {
    int e = blockIdx.x * blockDim.x + threadIdx.x;
    if (e < E) {
        int r = row[e], c = col[e];
        int pos = colptr[c] + rank[e];
        float nrm = dinv[r] * attr[e] * dinv[c];
        unsigned short nb = __half_as_ushort(__float2half(nrm));   // sign bit = 0
        csrX[pos] = (unsigned)r | ((unsigned)nb << 17);
        rank[e] = pos;
    }
}

// ---------- colof fill: colof[colptr[n]..colptr[n+1]) = n (contiguous runs) ----------

__global__ __launch_bounds__(256) void k_fill(const int* __restrict__ colptr,
                                              int* __restrict__ colof, int N) {
    int lane = threadIdx.x & 63;
    int wid  = (blockIdx.x * blockDim.x + threadIdx.x) >> 6;
    int nw   = (gridDim.x * blockDim.x) >> 6;
    for (int n = wid; n < N; n += nw) {
        int beg = colptr[n], end = colptr[n + 1];
        for (int p = beg + lane; p < end; p += 64) colof[p] = n;
    }
}

// ---------- encoder folding: g1 = x * (w_enc@W1) + b_enc@W1 (rank-1) ----------

__global__ void k_fold(const float* __restrict__ w_enc, const float* __restrict__ b_enc,
                       const float* __restrict__ W1,
                       float* __restrict__ we1, float* __restrict__ be1) {
    int j = threadIdx.x;
    if (j < L) {
        float a = 0.f, b = 0.f;
        for (int f = 0; f < L; ++f) {
            float wv = W1[f * L + j];
            a += w_enc[f] * wv;
            b += b_enc[f] * wv;
        }
        we1[j] = a; be1[j] = b;
    }
}

__global__ void k_encode(const float* __restrict__ x, const float* __restrict__ we1,
                         const float* __restrict__ be1, __half* __restrict__ g, int N) {
    int idx = blockIdx.x * blockDim.x + threadIdx.x;
    if (idx < N * L) {
        int n = idx >> 6, f = idx & 63;
        g[idx] = __float2half(x[n] * we1[f] + be1[f]);
    }
}

// ---------- gather-aggregate: h_out = relu(rcnt * sum(norm*g[row]) + b) ----------
// R7-proven structure; (256,8): 64-VGPR budget -> max waves for gather MLP
// (kernel is L1-request/latency-bound; more resident waves = more in flight).

__global__ __launch_bounds__(256, 8) void k_agg(const uint4* __restrict__ h4,
        __half* __restrict__ h_out, const float* __restrict__ bias,
        const int* __restrict__ colptr, const unsigned* __restrict__ csrX,
        const float* __restrict__ rcnt, int N) {
    int lane = threadIdx.x & 63;
    int grp  = lane >> 3;              // 8 groups of 8 lanes
    int sub  = lane & 7;               // 16B slice index within a row
    int wid  = (blockIdx.x * blockDim.x + threadIdx.x) >> 6;
    int nw   = (gridDim.x * blockDim.x) >> 6;

    float bl8[8];                      // bias for features 8*sub..8*sub+7
    #pragma unroll
    for (int i = 0; i < 8; ++i) bl8[i] = bias[8 * sub + i];

    int beg = 0, end = 0; unsigned mw = 0;
    if (wid < N) {
        beg = colptr[wid];
        end = colptr[wid + 1];
        if (beg + lane < end) mw = csrX[beg + lane];   // inactive lanes: 0 -> +0
    }

    for (int n = wid; n < N; n += nw) {
        int n2 = n + nw;
        int beg2 = 0, end2 = 0;
        if (n2 < N) { beg2 = colptr[n2]; end2 = colptr[n2 + 1]; }
        float rcv = rcnt[n];

        float va[8];
        #pragma unroll
        for (int i = 0; i < 8; ++i) va[i] = 0.f;

        auto PROC = [&](unsigned mwv, int mm) {
            int kmax = (mm + 7) >> 3;
            int k = 0;
            while (k < kmax) {
                int rem = kmax - k;    // wave-uniform branch
                if (rem >= 4) {
                    unsigned x0, x1, x2, x3; uint4 q0, q1, q2, q3;
                    GLOAD(x0, q0, k) GLOAD(x1, q1, k + 1)
                    GLOAD(x2, q2, k + 2) GLOAD(x3, q3, k + 3)
                    FMA8(va, q0, x0) FMA8(va, q1, x1)
                    FMA8(va, q2, x2) FMA8(va, q3, x3)
                    k += 4;
                } else if (rem == 3) {
                    unsigned x0, x1, x2; uint4 q0, q1, q2;
                    GLOAD(x0, q0, k) GLOAD(x1, q1, k + 1) GLOAD(x2, q2, k + 2)
                    FMA8(va, q0, x0) FMA8(va, q1, x1) FMA8(va, q2, x2)
                    k += 3;
                } else if (rem == 2) {
                    unsigned x0, x1; uint4 q0, q1;
                    GLOAD(x0, q0, k) GLOAD(x1, q1, k + 1)
                    FMA8(va, q0, x0) FMA8(va, q1, x1)
                    k += 2;
                } else {
                    unsigned x0; uint4 q0;
                    GLOAD(x0, q0, k)
                    FMA8(va, q0, x0)
                    k += 1;
                }
            }
        };

        int m = end - beg; if (m > 64) m = 64;
        PROC(mw, m);
        for (int base = beg + 64; base < end; base += 64) {   // rare (deg>64)
            int mm = end - base; if (mm > 64) mm = 64;
            unsigned mwc = 0;
            if (lane < mm) mwc = csrX[base + lane];
            PROC(mwc, mm);
        }

        unsigned mw2 = 0;
        if (n2 < N && beg2 + lane < end2) mw2 = csrX[beg2 + lane];

        float s[8];
        #pragma unroll
        for (int i = 0; i < 8; ++i) {
            float v = va[i];
            v += __shfl_xor(v, 8);
            v += __shfl_xor(v, 16);
            v += __shfl_xor(v, 32);
            s[i] = v;
        }
        if (lane < 8) {                // sub == lane: features 8*lane..8*lane+7
            unsigned u[4];
            #pragma unroll
            for (int i = 0; i < 4; ++i) {
                float oa = fmaxf(s[2 * i]     * rcv + bl8[2 * i],     0.f);
                float ob = fmaxf(s[2 * i + 1] * rcv + bl8[2 * i + 1], 0.f);
                u[i] = (unsigned)__half_as_ushort(__float2half(oa))
                     | ((unsigned)__half_as_ushort(__float2half(ob)) << 16);
            }
            uint4 st; st.x = u[0]; st.y = u[1]; st.z = u[2]; st.w = u[3];
            ((uint4*)h_out)[(size_t)n * 8 + lane] = st;
        }

        beg = beg2; end = end2; mw = mw2;
    }
}

// ---------- dense transform g = h @ W via MFMA (split-fp16 W: full f32 accuracy) ----------
// [N x 64] @ [64 x 64]: wave tile = 16 nodes. A: lane holds 8 K-contiguous fp16
// at row=lane&15, k-offset=(lane>>4)*8. W = Wh + Wl (fp16 hi + residual).
// D: col=lane&15, row=(lane>>4)*4+reg. Verified in production R12 (absmax same).

__global__ __launch_bounds__(256) void k_gx(const __half* __restrict__ h,
        const float* __restrict__ W, __half* __restrict__ g, int N) {
    int lane = threadIdx.x & 63;
    int wid  = (blockIdx.x * blockDim.x + threadIdx.x) >> 6;
    int nw   = (gridDim.x * blockDim.x) >> 6;
    int r16  = lane & 15;
    int q4   = lane >> 4;

    f16x8 bh[4][2], bl[4][2];          // B frags: [col-tile][k-step]
    #pragma unroll
    for (int t = 0; t < 4; ++t)
        #pragma unroll
        for (int ks = 0; ks < 2; ++ks)
            #pragma unroll
            for (int i = 0; i < 8; ++i) {
                int k = ks * 32 + q4 * 8 + i;
                float wv = W[k * L + t * 16 + r16];
                _Float16 hi = (_Float16)wv;
                bh[t][ks][i] = hi;
                bl[t][ks][i] = (_Float16)(wv - (float)hi);
            }

    int tiles = (N + 15) >> 4;
    for (int tt = wid; tt < tiles; tt += nw) {
        int n0 = tt << 4;
        int row = n0 + r16; if (row >= N) row = N - 1;
        f16x8 a0 = *(const f16x8*)(h + (size_t)row * L + q4 * 8);
        f16x8 a1 = *(const f16x8*)(h + (size_t)row * L + 32 + q4 * 8);
        #pragma unroll
        for (int t = 0; t < 4; ++t) {
            f32x4 acc = {0.f, 0.f, 0.f, 0.f};
            acc = __builtin_amdgcn_mfma_f32_16x16x32_f16(a0, bl[t][0], acc, 0, 0, 0);
            acc = __builtin_amdgcn_mfma_f32_16x16x32_f16(a1, bl[t][1], acc, 0, 0, 0);
            acc = __builtin_amdgcn_mfma_f32_16x16x32_f16(a0, bh[t][0], acc, 0, 0, 0);
            acc = __builtin_amdgcn_mfma_f32_16x16x32_f16(a1, bh[t][1], acc, 0, 0, 0);
            #pragma unroll
            for (int r = 0; r < 4; ++r) {
                int node = n0 + q4 * 4 + r;
                if (node < N)
                    g[(size_t)node * L + t * 16 + r16] = __float2half(acc[r]);
            }
        }
    }
}

// ---------- decoder node matvecs via MFMA (R13): U = h@W1[:64]+b1, V = h@W1[64:] ----------
// Two sequential phases reuse the same 64-VGPR B-frag block (Wu then Wv).
// Same verified fragment layouts + split-fp16 accuracy as k_gx.

__global__ __launch_bounds__(256) void k_mv2(const __half* __restrict__ h,
        const float* __restrict__ W1, const float* __restrict__ b1,
        __half* __restrict__ U, __half* __restrict__ V, int N) {
    int lane = threadIdx.x & 63;
    int wid  = (blockIdx.x * blockDim.x + threadIdx.x) >> 6;
    int nw   = (gridDim.x * blockDim.x) >> 6;
    int r16  = lane & 15;
    int q4   = lane >> 4;
    int tiles = (N + 15) >> 4;

    for (int phase = 0; phase < 2; ++phase) {
        const float* W = W1 + (size_t)phase * L * L;   // Wu rows 0..63, Wv rows 64..127
        __half* O = phase ? V : U;
        f16x8 bh[4][2], bl[4][2];
        float bv[4];
        #pragma unroll
        for (int t = 0; t < 4; ++t) {
            bv[t] = phase ? 0.f : b1[t * 16 + r16];
            #pragma unroll
            for (int ks = 0; ks < 2; ++ks)
                #pragma unroll
                for (int i = 0; i < 8; ++i) {
                    int k = ks * 32 + q4 * 8 + i;
                    float wv = W[k * L + t * 16 + r16];
                    _Float16 hi = (_Float16)wv;
                    bh[t][ks][i] = hi;
                    bl[t][ks][i] = (_Float16)(wv - (float)hi);
                }
        }
        for (int tt = wid; tt < tiles; tt += nw) {
            int n0 = tt << 4;
            int row = n0 + r16; if (row >= N) row = N - 1;
            f16x8 a0 = *(const f16x8*)(h + (size_t)row * L + q4 * 8);
            f16x8 a1 = *(const f16x8*)(h + (size_t)row * L + 32 + q4 * 8);
            #pragma unroll
            for (int t = 0; t < 4; ++t) {
                f32x4 acc = {0.f, 0.f, 0.f, 0.f};
                acc = __builtin_amdgcn_mfma_f32_16x16x32_f16(a0, bl[t][0], acc, 0, 0, 0);
                acc = __builtin_amdgcn_mfma_f32_16x16x32_f16(a1, bl[t][1], acc, 0, 0, 0);
                acc = __builtin_amdgcn_mfma_f32_16x16x32_f16(a0, bh[t][0], acc, 0, 0, 0);
                acc = __builtin_amdgcn_mfma_f32_16x16x32_f16(a1, bh[t][1], acc, 0, 0, 0);
                #pragma unroll
                for (int r = 0; r < 4; ++r) {
                    int node = n0 + q4 * 4 + r;
                    if (node < N)
                        O[(size_t)node * L + t * 16 + r16] = __float2half(acc[r] + bv[t]);
                }
            }
        }
    }
}

// ---------- decoder edge pass: EDGE-PARALLEL, 8 lanes per CSR position ----------

__global__ __launch_bounds__(256, 8) void k_edge(const __half* __restrict__ U,
        const __half* __restrict__ V, const float* __restrict__ w2,
        const float* __restrict__ b2, const unsigned* __restrict__ csrX,
        const int* __restrict__ colof, float* __restrict__ tmp, int E) {
    int sub = threadIdx.x & 7;
    float w2f[8];
    #pragma unroll
    for (int i = 0; i < 8; ++i) w2f[i] = w2[8 * sub + i];
    float b2v = b2[0];
    int tid = blockIdx.x * blockDim.x + threadIdx.x;
    int np  = (gridDim.x * blockDim.x) >> 3;
    for (int p = tid >> 3; p < E; p += np) {
        unsigned md = csrX[p];
        int r = (int)(md & 0x1FFFFu);
        int n = colof[p];
        uint4 uq = ((const uint4*)(U + (size_t)r * L))[sub];
        uint4 vq = ((const uint4*)(V + (size_t)n * L))[sub];
        float p0 = 0.f, p1 = 0.f;
        #define DOT2X(uw_, vw_, B) { unsigned t_; \
            PKADDRELU(t_, (uw_), (vw_)); \
            FMAMIX_LO(p0, t_, w2f[B]); FMAMIX_HI(p1, t_, w2f[(B) + 1]); }
        DOT2X(uq.x, vq.x, 0) DOT2X(uq.y, vq.y, 2)
        DOT2X(uq.z, vq.z, 4) DOT2X(uq.w, vq.w, 6)
        #undef DOT2X
        float pd = p0 + p1;
        pd += __shfl_xor(pd, 1);
        pd += __shfl_xor(pd, 2);
        pd += __shfl_xor(pd, 4);
        if (sub == 0) tmp[p] = pd + b2v;
    }
}

// ---------- permute CSR-ordered results back to edge order (+ softplus) ----------

__global__ void k_perm(const int* __restrict__ epos, const float* __restrict__ tmp,
                       const int* __restrict__ erow, const int* __restrict__ ecol,
                       float* __restrict__ out, int E) {
    int e = blockIdx.x * blockDim.x + threadIdx.x;
    if (e < E) {
        float val = tmp[epos[e]];
        if (erow[e] == ecol[e])
            val = fmaxf(val, 0.f) + log1pf(expf(-fabsf(val)));
        out[e] = val;
    }
}

// ---------- launch ----------

extern "C" void kernel_launch(void* const* d_in, const int* in_sizes, int n_in,
                              void* d_out, int out_size, void* d_ws, size_t ws_size,
                              hipStream_t stream) {
    const float* x     = (const float*)d_in[0];
    const float* attr  = (const float*)d_in[1];
    const float* w_enc = (const float*)d_in[2];
    const float* b_enc = (const float*)d_in[3];
    const float* c1w   = (const float*)d_in[4];
    const float* c1b   = (const float*)d_in[5];
    const float* c2w   = (const float*)d_in[6];
    const float* c2b   = (const float*)d_in[7];
    const float* dw1   = (const float*)d_in[8];
    const float* db1   = (const float*)d_in[9];
    const float* dw2   = (const float*)d_in[10];
    const float* db2   = (const float*)d_in[11];
    const int*   erow  = (const int*)d_in[12];
    const int*   ecol  = (const int*)d_in[13];
    int N = in_sizes[0];
    int E = in_sizes[1];
    float* out = (float*)d_out;

    char* w = (char*)d_ws;
    auto alloc = [&](size_t bytes) {
        char* p = w; w += (bytes + 255) & ~(size_t)255; return p;
    };
    unsigned* degcnt = (unsigned*)alloc((size_t)N * 4);  // zeroed
    size_t zbytes = (size_t)(w - (char*)d_ws);
    float* dinv   = (float*)alloc((size_t)N * 4);
    int*   cntI   = (int*)  alloc((size_t)N * 4);
    float* rcnt   = (float*)alloc((size_t)N * 4);
    int*   colptr = (int*)  alloc((size_t)(N + 1) * 4);
    int*   bsums  = (int*)  alloc(((size_t)(N + 1023) / 1024 + 1) * 4);
    float* we1    = (float*)alloc(L * 4);
    float* be1    = (float*)alloc(L * 4);
    int*   rank   = (int*)  alloc((size_t)E * 4);   // per-col rank, then abs CSR pos
    unsigned* csrX = (unsigned*)alloc((size_t)E * 4);
    int*   colof  = (int*)  alloc((size_t)E * 4);   // owning col per CSR position
    float* tmp    = (float*)alloc((size_t)E * 4);
    __half* hA    = (__half*)alloc((size_t)N * L * 2);   // fp16 h ping
    __half* hB    = (__half*)alloc((size_t)N * L * 2);   // fp16 h pong
    __half* hU    = (__half*)alloc((size_t)N * L * 2);   // decoder U; aliases g
    __half* hV    = (__half*)alloc((size_t)N * L * 2);   // decoder V (fp16)
    __half* gbuf  = hU;   // g buffer lives in hU until k_mv2 (which reads hB)
    (void)ws_size; (void)n_in; (void)out_size;

    (void)hipMemsetAsync(d_ws, 0, zbytes, stream);

    int eb = (E + 255) / 256;
    int nb = (N + 255) / 256;
    int B  = (N + 1023) / 1024;     // scan chunks
    k_hist<<<eb, 256, 0, stream>>>(ecol, attr, degcnt, rank, E);
    k_dinv<<<nb, 256, 0, stream>>>(degcnt, dinv, cntI, rcnt, N);
    k_scan_a<<<B, 256, 0, stream>>>(cntI, bsums, N);
    k_scan_b<<<1, 1024, 0, stream>>>(bsums, B, colptr, N);
    k_scan_c<<<B, 256, 0, stream>>>(cntI, bsums, colptr, N);
    k_scatter<<<eb, 256, 0, stream>>>(erow, ecol, attr, dinv, colptr, rank, csrX, E);
    k_fill<<<1024, 256, 0, stream>>>(colptr, colof, N);

    // encoder folded with conv1_0's W: g1 = x * (w_enc@W) + b_enc@W
    k_fold<<<1, 64, 0, stream>>>(w_enc, b_enc, c1w, we1, be1);
    k_encode<<<(N * L + 255) / 256, 256, 0, stream>>>(x, we1, be1, gbuf, N);

    // 6 conv layers: agg(g) -> h; then g = h @ W_next (except after the last)
    const float* Ws[6] = {c1w,             c2w,
                          c1w + L * L,     c2w + L * L,
                          c1w + 2 * L * L, c2w + 2 * L * L};
    const float* Bs[6] = {c1b,         c2b,
                          c1b + L,     c2b + L,
                          c1b + 2 * L, c2b + 2 * L};
    (void)Ws[0];   // folded into the encoder
    __half* outs[2] = {hA, hB};
    __half* hcur = nullptr;
    for (int j = 0; j < 6; ++j) {
        hcur = outs[j & 1];
        k_agg<<<2048, 256, 0, stream>>>((const uint4*)gbuf, hcur, Bs[j],
                                        colptr, csrX, rcnt, N);
        if (j < 5)
            k_gx<<<512, 256, 0, stream>>>(hcur, Ws[j + 1], gbuf, N);
    }
    // h_final in hcur (= hB). U -> hU (b1 folded), V -> hV
    k_mv2<<<512, 256, 0, stream>>>(hcur, dw1, db1, hU, hV, N);
    k_edge<<<2048, 256, 0, stream>>>(hU, hV, dw2, db2, csrX, colof, tmp, E);
    k_perm<<<eb, 256, 0, stream>>>(rank, tmp, erow, ecol, out, E);
}